// Round 5
// baseline (261.840 us; speedup 1.0000x reference)
//
#include <hip/hip_runtime.h>
#include <math.h>

typedef __attribute__((ext_vector_type(8))) short short8;
typedef __attribute__((ext_vector_type(4))) float float4v;
typedef __attribute__((ext_vector_type(4))) unsigned short ushort4v;

static __device__ __forceinline__ unsigned short f2bf(float f) {
    union { float f; unsigned u; } v; v.f = f;
    unsigned u = v.u;
    return (unsigned short)((u + 0x7fffu + ((u >> 16) & 1u)) >> 16);
}
static __device__ __forceinline__ float bf2f(unsigned short h) {
    union { unsigned u; float f; } v; v.u = ((unsigned)h) << 16;
    return v.f;
}

// ---------------------------------------------------------------------------
// Graph structure (compile-time), matching Python enumeration order.
// ---------------------------------------------------------------------------
struct AdjT {
    int src[120];
    int dst[120];
    int cnt[36];
    int idx[36][4];    // incoming edges per node
    int ostart[36];    // outgoing edge run start
    int ocnt[36];      // outgoing edge run length
};

constexpr AdjT build_adj() {
    AdjT a{};
    const int ddx[4] = {-1, 0, 0, 1};
    const int ddy[4] = {0, -1, 1, 0};
    int ne = 0;
    for (int i = 0; i < 6; i++)
        for (int j = 0; j < 6; j++)
            for (int d = 0; d < 4; d++) {
                int x = i + ddx[d], y = j + ddy[d];
                if (x >= 0 && x < 6 && y >= 0 && y < 6) {
                    a.src[ne] = j * 6 + i;
                    a.dst[ne] = y * 6 + x;
                    ne++;
                }
            }
    for (int n = 0; n < 36; n++) {
        a.cnt[n] = 0;
        for (int e = 0; e < 120; e++)
            if (a.dst[e] == n) a.idx[n][a.cnt[n]++] = e;
    }
    for (int n = 0; n < 36; n++) { a.ostart[n] = 0; a.ocnt[n] = 0; }
    for (int e = 0; e < 120; e++) {
        a.ocnt[a.src[e]]++;
        if (e == 0 || a.src[e] != a.src[e - 1]) a.ostart[a.src[e]] = e;
    }
    return a;
}

__device__ constexpr AdjT ADJC = build_adj();
__device__ constexpr int G16_START[17] =
    {0, 3, 6, 9, 12, 14, 16, 18, 20, 22, 24, 26, 28, 30, 32, 34, 36};

// ---------------------------------------------------------------------------
// K0: weight prep — B-fragments (bf16) for conv2/conv3/conv4 MFMA.
// ---------------------------------------------------------------------------
__global__ __launch_bounds__(256) void k_prep(const float* __restrict__ w2,
                                              const float* __restrict__ w3,
                                              const float* __restrict__ w4,
                                              unsigned short* __restrict__ wp2,
                                              unsigned short* __restrict__ wp3,
                                              unsigned short* __restrict__ wp4) {
    int e = blockIdx.x * 256 + threadIdx.x;
    if (e < 25600) {
        int j = e & 7, lane = (e >> 3) & 63, ct = (e >> 9) & 1, t = e >> 10;
        int co = ct * 16 + (lane & 15), ci = (lane >> 4) * 8 + j;
        wp2[e] = f2bf(w2[co * 800 + ci * 25 + t]);
    } else if (e < 76800) {
        int e3 = e - 25600;
        int j = e3 & 7, lane = (e3 >> 3) & 63, nt = (e3 >> 9) & 3, t = e3 >> 11;
        int co = nt * 16 + (lane & 15), ci = (lane >> 4) * 8 + j;
        wp3[e3] = f2bf(w3[(co * 32 + ci) * 25 + t]);
    } else {
        int e4 = e - 76800;
        int j = e4 & 7, lane = (e4 >> 3) & 63, nt = (e4 >> 9) & 3;
        int ks = (e4 >> 11) & 1, t = e4 >> 12;
        int co = nt * 16 + (lane & 15), ci = ks * 32 + (lane >> 4) * 8 + j;
        wp4[e4] = f2bf(w4[(co * 64 + ci) * 25 + t]);
    }
}

// ---------------------------------------------------------------------------
// K0b: weight prep for heads MFMA (verified R4).
// ---------------------------------------------------------------------------
__global__ __launch_bounds__(256) void k_prep2(const float* __restrict__ cnw1,
                                               const float* __restrict__ epw1,
                                               const float* __restrict__ cnw2,
                                               const float* __restrict__ epw2,
                                               unsigned short* __restrict__ wph1,
                                               unsigned short* __restrict__ wpcn2,
                                               unsigned short* __restrict__ wpep2) {
    int e = blockIdx.x * 256 + threadIdx.x;
    if (e < 131072) {
        int j = e & 7, lane = (e >> 3) & 63, nt = (e >> 9) & 31, kt = e >> 14;
        int c = nt * 16 + (lane & 15);
        int k = kt * 32 + ((lane >> 4) << 3) + j;
        float v = (c < 256) ? cnw1[c * 256 + k] : epw1[(c - 256) * 256 + k];
        wph1[e] = f2bf(v);
    } else if (e < 163840) {
        int e2 = e - 131072;
        int j = e2 & 7, lane = (e2 >> 3) & 63, nt = (e2 >> 9) & 7, kt = e2 >> 12;
        int c = nt * 16 + (lane & 15);
        int k = kt * 32 + ((lane >> 4) << 3) + j;
        wpcn2[e2] = f2bf(c < 120 ? cnw2[c * 256 + k] : 0.f);
    } else {
        int e3 = e - 163840;
        int j = e3 & 7, lane = (e3 >> 3) & 63, idx = e3 >> 9;
        int kt = idx / 3, nt = idx - kt * 3;
        int c = nt * 16 + (lane & 15);
        int k = kt * 32 + ((lane >> 4) << 3) + j;
        wpep2[e3] = f2bf(c < 36 ? epw2[c * 256 + k] : 0.f);
    }
}

// ---------------------------------------------------------------------------
// K1: conv1 [B,1,32,32] -> channel-last bf16 [B, 784 pos, 32 ci]
// Position-major: thread = (row y, 4-col group). Window 5x8 in registers
// (float4 loads, s_img stride 36 for bank spread); weights via wave-uniform
// scalar loads; outputs packed bf16x2, 16B stores.
// ---------------------------------------------------------------------------
__global__ __launch_bounds__(256) void k_conv1(const float* __restrict__ img,
                                               const float* __restrict__ w,
                                               const float* __restrict__ bias,
                                               unsigned short* __restrict__ out) {
    __shared__ float s_img[32 * 36];
    const int b = blockIdx.x, tid = threadIdx.x;
    const float* ip = img + (size_t)b * 1024;
    for (int t = tid; t < 1024; t += 256) {
        int row = t >> 5, col = t & 31;
        s_img[row * 36 + col] = ip[t];
    }
    __syncthreads();
    if (tid >= 196) return;
    const int y = tid / 7, xg = (tid - y * 7) * 4;

    float win[5][8];
#pragma unroll
    for (int r = 0; r < 5; r++) {
        float4 v0 = *(const float4*)(s_img + (y + r) * 36 + xg);
        float4 v1 = *(const float4*)(s_img + (y + r) * 36 + xg + 4);
        win[r][0] = v0.x; win[r][1] = v0.y; win[r][2] = v0.z; win[r][3] = v0.w;
        win[r][4] = v1.x; win[r][5] = v1.y; win[r][6] = v1.z; win[r][7] = v1.w;
    }

    unsigned res[4][16];  // [pos in group][co pair] packed bf16x2
#pragma unroll 4
    for (int cp = 0; cp < 16; cp++) {
        float b0 = bias[2 * cp], b1 = bias[2 * cp + 1];
        float acc0[4], acc1[4];
#pragma unroll
        for (int p = 0; p < 4; p++) { acc0[p] = b0; acc1[p] = b1; }
        const float* w0 = w + (2 * cp) * 25;
        const float* w1 = w0 + 25;
#pragma unroll
        for (int ky = 0; ky < 5; ky++)
#pragma unroll
            for (int kx = 0; kx < 5; kx++) {
                float wv0 = w0[ky * 5 + kx], wv1 = w1[ky * 5 + kx];
#pragma unroll
                for (int p = 0; p < 4; p++) {
                    float iv = win[ky][kx + p];
                    acc0[p] += iv * wv0;
                    acc1[p] += iv * wv1;
                }
            }
#pragma unroll
        for (int p = 0; p < 4; p++)
            res[p][cp] = (unsigned)f2bf(acc0[p]) | ((unsigned)f2bf(acc1[p]) << 16);
    }

    unsigned short* op = out + (size_t)b * 25088;
#pragma unroll
    for (int p = 0; p < 4; p++) {
        unsigned* dst = (unsigned*)(op + (y * 28 + xg + p) * 32);
#pragma unroll
        for (int v = 0; v < 4; v++)
            ((uint4*)dst)[v] = make_uint4(res[p][v * 4], res[p][v * 4 + 1],
                                          res[p][v * 4 + 2], res[p][v * 4 + 3]);
    }
}

// ---------------------------------------------------------------------------
// K2: conv2 + maxpool2 via MFMA tap-GEMM.
// R5 changes: s_in row stride 32 -> 40 ushorts (80 B = 20 dwords; pos*20 mod 32
// covers all multiples of 4 => A-frag b128 reads are exact 2-way = free, and
// 16 B alignment preserved). s_stage unioned onto s_in (live ranges disjoint,
// extra barrier) => LDS 47104 -> 35840 B, 3 -> 4 blocks/CU.
// ---------------------------------------------------------------------------
__global__ __launch_bounds__(128) void k_conv2(const unsigned short* __restrict__ in,
                                               const unsigned short* __restrict__ wprep,
                                               const float* __restrict__ bias,
                                               unsigned short* __restrict__ out) {
    __shared__ unsigned short s_buf[448 * 40];  // s_in [448][40]; later s_stage [288][40]
    const int blk = blockIdx.x;
    const int b = blk >> 1, half = blk & 1;
    const int tid = threadIdx.x;
    const int lane = tid & 63, wave = tid >> 6;
    const int m = lane & 15, quad = lane >> 4;

    // stage 16 input rows (448 positions, ch-last) at stride 40
    {
        const short8* g8 = (const short8*)(in + (size_t)b * 25088 + half * 12 * 28 * 32);
        for (int i = tid; i < 1792; i += 128) {
            int pos = i >> 2, part = i & 3;
            *(short8*)(s_buf + pos * 40 + part * 8) = g8[i];
        }
    }

    int a_idx[9];
#pragma unroll
    for (int mt = 0; mt < 9; mt++) {
        int p = wave * 144 + mt * 16 + m;
        int yl = p / 24;
        int x = p - yl * 24;
        a_idx[mt] = (yl * 28 + x) * 40 + quad * 8;
    }

    float4v acc[9][2];
#pragma unroll
    for (int mt = 0; mt < 9; mt++) {
        acc[mt][0] = (float4v){0.f, 0.f, 0.f, 0.f};
        acc[mt][1] = (float4v){0.f, 0.f, 0.f, 0.f};
    }

    const short8* wp = (const short8*)wprep;
    short8 bw0 = wp[lane];
    short8 bw1 = wp[64 + lane];

    __syncthreads();

    for (int t = 0; t < 25; t++) {
        short8 nb0, nb1;
        if (t < 24) {
            nb0 = wp[(t + 1) * 128 + lane];
            nb1 = wp[(t + 1) * 128 + 64 + lane];
        }
        const int ky = t / 5, kx = t - ky * 5;
        const int toff = (ky * 28 + kx) * 40;
#pragma unroll
        for (int mt = 0; mt < 9; mt++) {
            short8 av = *(const short8*)(s_buf + a_idx[mt] + toff);
            acc[mt][0] = __builtin_amdgcn_mfma_f32_16x16x32_bf16(av, bw0, acc[mt][0], 0, 0, 0);
            acc[mt][1] = __builtin_amdgcn_mfma_f32_16x16x32_bf16(av, bw1, acc[mt][1], 0, 0, 0);
        }
        if (t < 24) { bw0 = nb0; bw1 = nb1; }
    }

    __syncthreads();  // all A-reads done before s_stage overwrites s_in

    const int n = lane & 15;
#pragma unroll
    for (int mt = 0; mt < 9; mt++) {
        int pbase = wave * 144 + mt * 16 + quad * 4;
#pragma unroll
        for (int r = 0; r < 4; r++) {
            s_buf[(pbase + r) * 40 + n] = f2bf(acc[mt][0][r]);
            s_buf[(pbase + r) * 40 + 16 + n] = f2bf(acc[mt][1][r]);
        }
    }
    __syncthreads();

    unsigned short* op = out + (size_t)b * 4608;
    for (int i = tid; i < 2304; i += 128) {
        int co = i & 31;
        int pos = i >> 5;
        int prl = pos / 12;
        int px = pos - prl * 12;
        int base = ((prl * 2) * 24 + px * 2) * 40 + co;
        float v0 = bf2f(s_buf[base]);
        float v1 = bf2f(s_buf[base + 40]);
        float v2 = bf2f(s_buf[base + 24 * 40]);
        float v3 = bf2f(s_buf[base + 25 * 40]);
        float mx = fmaxf(fmaxf(v0, v1), fmaxf(v2, v3));
        op[((half * 6 + prl) * 12 + px) * 32 + co] = f2bf(mx + bias[co]);
    }
}

// ---------------------------------------------------------------------------
// K34: fused conv3 + conv4 + pool + flatten via MFMA tap-GEMM (verified R3/R4).
// R5: s_c4 unioned over s_in region (single-wave block; barrier before reuse)
// => LDS 22528 -> 18432 B.
// ---------------------------------------------------------------------------
__global__ __launch_bounds__(64) void k_conv34(const unsigned short* __restrict__ p2,
                                               const unsigned short* __restrict__ wp3,
                                               const float* __restrict__ b3,
                                               const unsigned short* __restrict__ wp4,
                                               const float* __restrict__ b4,
                                               unsigned short* __restrict__ emb) {
    __shared__ unsigned short s_buf34[9216];  // s_in [0,4608) | s_c3 [4608,9216)
    unsigned short* s_in = s_buf34;
    unsigned short* s_c3 = s_buf34 + 4608;    // [64][72] padded
    float* s_c4 = (float*)s_buf34;            // [16][64] — reuses s_in region
    const int b = blockIdx.x, tid = threadIdx.x;
    const int m = tid & 15, q = tid >> 4;

    {
        const short8* g8 = (const short8*)(p2 + (size_t)b * 4608);
        short8* s8 = (short8*)s_in;
        for (int i = tid; i < 576; i += 64) s8[i] = g8[i];
    }

    int a_base[4];
#pragma unroll
    for (int mt = 0; mt < 4; mt++) {
        int p = mt * 16 + m;
        int y = p >> 3, x = p & 7;
        a_base[mt] = (y * 12 + x) * 32 + q * 8;
    }

    float4v acc3[4][4];
#pragma unroll
    for (int mt = 0; mt < 4; mt++)
#pragma unroll
        for (int nt = 0; nt < 4; nt++) acc3[mt][nt] = (float4v){0.f, 0.f, 0.f, 0.f};

    const short8* wp = (const short8*)wp3;
    short8 bw[4];
#pragma unroll
    for (int nt = 0; nt < 4; nt++) bw[nt] = wp[nt * 64 + tid];

    __syncthreads();

    for (int t = 0; t < 25; t++) {
        short8 nb[4];
        if (t < 24) {
#pragma unroll
            for (int nt = 0; nt < 4; nt++) nb[nt] = wp[((t + 1) * 4 + nt) * 64 + tid];
        }
        const int ky = t / 5, kx = t - ky * 5;
        const int toff = (ky * 12 + kx) * 32;
#pragma unroll
        for (int mt = 0; mt < 4; mt++) {
            short8 av = *(const short8*)(s_in + a_base[mt] + toff);
#pragma unroll
            for (int nt = 0; nt < 4; nt++)
                acc3[mt][nt] = __builtin_amdgcn_mfma_f32_16x16x32_bf16(av, bw[nt], acc3[mt][nt], 0, 0, 0);
        }
        if (t < 24) {
#pragma unroll
            for (int nt = 0; nt < 4; nt++) bw[nt] = nb[nt];
        }
    }

    {
        float bb[4];
#pragma unroll
        for (int nt = 0; nt < 4; nt++) bb[nt] = b3[nt * 16 + m];
#pragma unroll
        for (int mt = 0; mt < 4; mt++)
#pragma unroll
            for (int nt = 0; nt < 4; nt++)
#pragma unroll
                for (int r = 0; r < 4; r++)
                    s_c3[(mt * 16 + q * 4 + r) * 72 + nt * 16 + m] =
                        f2bf(acc3[mt][nt][r] + bb[nt]);
    }
    __syncthreads();

    const int a4_base = ((m >> 2) * 8 + (m & 3)) * 72 + q * 8;
    float4v acc4[4];
#pragma unroll
    for (int nt = 0; nt < 4; nt++) acc4[nt] = (float4v){0.f, 0.f, 0.f, 0.f};

    const short8* wq = (const short8*)wp4;
    short8 cw[8];
#pragma unroll
    for (int i = 0; i < 8; i++) cw[i] = wq[i * 64 + tid];

    for (int t = 0; t < 25; t++) {
        short8 nb[8];
        if (t < 24) {
#pragma unroll
            for (int i = 0; i < 8; i++) nb[i] = wq[((t + 1) * 8 + i) * 64 + tid];
        }
        const int ky = t / 5, kx = t - ky * 5;
        const int toff = (ky * 8 + kx) * 72;
#pragma unroll
        for (int ks = 0; ks < 2; ks++) {
            short8 av = *(const short8*)(s_c3 + a4_base + toff + ks * 32);
#pragma unroll
            for (int nt = 0; nt < 4; nt++)
                acc4[nt] = __builtin_amdgcn_mfma_f32_16x16x32_bf16(av, cw[ks * 4 + nt], acc4[nt], 0, 0, 0);
        }
        if (t < 24) {
#pragma unroll
            for (int i = 0; i < 8; i++) cw[i] = nb[i];
        }
    }

    __syncthreads();  // s_in reads (phase A) & s_c3 reads done before s_c4 reuse

#pragma unroll
    for (int nt = 0; nt < 4; nt++)
#pragma unroll
        for (int r = 0; r < 4; r++)
            s_c4[(q * 4 + r) * 64 + nt * 16 + m] = acc4[nt][r];
    __syncthreads();

    {
        float bb = b4[tid];
        ushort4v res;
#pragma unroll
        for (int pp = 0; pp < 4; pp++) {
            int y0 = (pp >> 1) * 2, x0 = (pp & 1) * 2;
            float v0 = s_c4[(y0 * 4 + x0) * 64 + tid];
            float v1 = s_c4[(y0 * 4 + x0 + 1) * 64 + tid];
            float v2 = s_c4[((y0 + 1) * 4 + x0) * 64 + tid];
            float v3 = s_c4[((y0 + 1) * 4 + x0 + 1) * 64 + tid];
            res[pp] = f2bf(fmaxf(fmaxf(v0, v1), fmaxf(v2, v3)) + bb);
        }
        *(ushort4v*)(emb + (size_t)b * 256 + tid * 4) = res;
    }
}

// ---------------------------------------------------------------------------
// K5: fused heads (MFMA) + DAMP recurrence (verified R4).
// ---------------------------------------------------------------------------
__global__ __launch_bounds__(256) void k_heads(
    const unsigned short* __restrict__ emb,
    const unsigned short* __restrict__ wph1,
    const float* __restrict__ cn_b1, const float* __restrict__ ep_b1,
    const unsigned short* __restrict__ wpcn2, const float* __restrict__ cn_b2,
    const unsigned short* __restrict__ wpep2, const float* __restrict__ ep_b2,
    float* __restrict__ out) {
    __shared__ unsigned short s_hid[16 * 520];
    __shared__ float s_conn[120 * 17];
    __shared__ float s_rec0[120 * 17];
    __shared__ float s_rec1[120 * 17];
    __shared__ float s_ep[36 * 17];
    const int tid = threadIdx.x;
    const int lane = tid & 63, wave = tid >> 6;
    const int m = lane & 15, q = lane >> 4;
    const int b0 = blockIdx.x * 16;

    float4v acc[8];
#pragma unroll
    for (int i = 0; i < 8; i++) acc[i] = (float4v){0.f, 0.f, 0.f, 0.f};
    const short8* wp1 = (const short8*)wph1;
    for (int kt = 0; kt < 8; kt++) {
        short8 av = *(const short8*)(emb + (size_t)(b0 + m) * 256 + kt * 32 + q * 8);
#pragma unroll
        for (int ntl = 0; ntl < 8; ntl++) {
            int nt = wave * 8 + ntl;
            short8 bv = wp1[(kt * 32 + nt) * 64 + lane];
            acc[ntl] = __builtin_amdgcn_mfma_f32_16x16x32_bf16(av, bv, acc[ntl], 0, 0, 0);
        }
    }
#pragma unroll
    for (int ntl = 0; ntl < 8; ntl++) {
        int c = (wave * 8 + ntl) * 16 + m;
        float bb = (c < 256) ? cn_b1[c] : ep_b1[c - 256];
#pragma unroll
        for (int r = 0; r < 4; r++)
            s_hid[(q * 4 + r) * 520 + c] = f2bf(fmaxf(acc[ntl][r] + bb, 0.f));
    }
    __syncthreads();

    for (int job = wave; job < 11; job += 4) {
        const bool isconn = job < 8;
        const int koff = isconn ? 0 : 256;
        float4v a2 = (float4v){0.f, 0.f, 0.f, 0.f};
        for (int kt = 0; kt < 8; kt++) {
            short8 av = *(const short8*)(s_hid + m * 520 + koff + kt * 32 + q * 8);
            short8 bv = isconn
                ? ((const short8*)wpcn2)[(kt * 8 + job) * 64 + lane]
                : ((const short8*)wpep2)[(kt * 3 + (job - 8)) * 64 + lane];
            a2 = __builtin_amdgcn_mfma_f32_16x16x32_bf16(av, bv, a2, 0, 0, 0);
        }
        int c = (isconn ? job : (job - 8)) * 16 + m;
        float bb = isconn ? (c < 120 ? cn_b2[c] : 0.f) : (c < 36 ? ep_b2[c] : 0.f);
#pragma unroll
        for (int r = 0; r < 4; r++) {
            float v = 1.f / (1.f + __expf(-(a2[r] + bb)));
            int row = q * 4 + r;
            if (isconn) {
                if (c < 120) { s_conn[c * 17 + row] = v; s_rec0[c * 17 + row] = v; }
            } else {
                if (c < 36) s_ep[c * 17 + row] = v;
            }
        }
    }
    __syncthreads();

    const int row = tid >> 4, g = tid & 15;
    const int ns = G16_START[g];
    const int nodecnt = G16_START[g + 1] - ns;
    int ie[3][4], icnt[3], os[3], oc[3];
    float cr[3][4];
#pragma unroll
    for (int s = 0; s < 3; s++) {
        if (s < nodecnt) {
            int n = ns + s;
            icnt[s] = ADJC.cnt[n];
#pragma unroll
            for (int qx = 0; qx < 4; qx++) ie[s][qx] = ADJC.idx[n][qx];
            os[s] = ADJC.ostart[n];
            oc[s] = ADJC.ocnt[n];
#pragma unroll
            for (int oe = 0; oe < 4; oe++)
                cr[s][oe] = (oe < oc[s]) ? s_conn[(os[s] + oe) * 17 + row] : 0.f;
        } else {
            icnt[s] = 0; oc[s] = 0; os[s] = 0;
#pragma unroll
            for (int qx = 0; qx < 4; qx++) ie[s][qx] = 0;
#pragma unroll
            for (int oe = 0; oe < 4; oe++) cr[s][oe] = 0.f;
        }
    }
    float old0 = (g == 0) ? s_conn[0 * 17 + row] : 0.f;

    for (int it = 0; it < 36; it++) {
        const float* cur = (it & 1) ? s_rec1 : s_rec0;
        float* nxt = (it & 1) ? s_rec0 : s_rec1;
#pragma unroll
        for (int s = 0; s < 3; s++) {
            float sum = 0.f;
#pragma unroll
            for (int qx = 0; qx < 4; qx++)
                sum += (qx < icnt[s]) ? cur[ie[s][qx] * 17 + row] : 0.f;
            sum = fminf(sum, 1.f);
#pragma unroll
            for (int oe = 0; oe < 4; oe++) {
                if (oe < oc[s]) {
                    int e = os[s] + oe;
                    float nv = sum * cr[s][oe];
                    nxt[e * 17 + row] = nv;
                    if (g == 0 && s == 0 && oe == 0)
                        old0 = fminf(old0 + nv, 1.f);
                }
            }
        }
        __syncthreads();
    }

    if (g == 0)
        out[b0 + row] = old0 * s_ep[0 * 17 + row] * s_ep[6 * 17 + row];
}

// ---------------------------------------------------------------------------
extern "C" void kernel_launch(void* const* d_in, const int* in_sizes, int n_in,
                              void* d_out, int out_size, void* d_ws, size_t ws_size,
                              hipStream_t stream) {
    const float* image = (const float*)d_in[0];
    const float* c1w = (const float*)d_in[1];
    const float* c1b = (const float*)d_in[2];
    const float* c2w = (const float*)d_in[3];
    const float* c2b = (const float*)d_in[4];
    const float* c3w = (const float*)d_in[5];
    const float* c3b = (const float*)d_in[6];
    const float* c4w = (const float*)d_in[7];
    const float* c4b = (const float*)d_in[8];
    const float* epw1 = (const float*)d_in[9];
    const float* epb1 = (const float*)d_in[10];
    const float* epw2 = (const float*)d_in[11];
    const float* epb2 = (const float*)d_in[12];
    const float* cnw1 = (const float*)d_in[13];
    const float* cnb1 = (const float*)d_in[14];
    const float* cnw2 = (const float*)d_in[15];
    const float* cnb2 = (const float*)d_in[16];

    const int B = in_sizes[0] / (32 * 32);  // 1024

    unsigned short* ws = (unsigned short*)d_ws;
    unsigned short* conv1o = ws;                          // B*25088 bf16
    unsigned short* p2 = conv1o + (size_t)B * 25088;      // B*4608 bf16
    unsigned short* embo = p2 + (size_t)B * 4608;         // B*256 bf16
    unsigned short* wp2 = embo + (size_t)B * 256;         // 25600
    unsigned short* wp3 = wp2 + 25600;                    // 51200
    unsigned short* wp4 = wp3 + 51200;                    // 102400
    unsigned short* wph1 = wp4 + 102400;                  // 131072
    unsigned short* wpcn2 = wph1 + 131072;                // 32768
    unsigned short* wpep2 = wpcn2 + 32768;                // 12288

    k_prep<<<700, 256, 0, stream>>>(c2w, c3w, c4w, wp2, wp3, wp4);
    k_prep2<<<688, 256, 0, stream>>>(cnw1, epw1, cnw2, epw2, wph1, wpcn2, wpep2);
    k_conv1<<<B, 256, 0, stream>>>(image, c1w, c1b, conv1o);
    k_conv2<<<B * 2, 128, 0, stream>>>(conv1o, wp2, c2b, p2);
    k_conv34<<<B, 64, 0, stream>>>(p2, wp3, c3b, wp4, c4b, embo);
    k_heads<<<B / 16, 256, 0, stream>>>(embo, wph1, cnb1, epb1,
                                        wpcn2, cnb2, wpep2, epb2, (float*)d_out);
}

// Round 6
// 255.436 us; speedup vs baseline: 1.0251x; 1.0251x over previous
//
#include <hip/hip_runtime.h>
#include <math.h>

typedef __attribute__((ext_vector_type(8))) short short8;
typedef __attribute__((ext_vector_type(4))) float float4v;
typedef __attribute__((ext_vector_type(4))) unsigned short ushort4v;

static __device__ __forceinline__ unsigned short f2bf(float f) {
    union { float f; unsigned u; } v; v.f = f;
    unsigned u = v.u;
    return (unsigned short)((u + 0x7fffu + ((u >> 16) & 1u)) >> 16);
}
static __device__ __forceinline__ float bf2f(unsigned short h) {
    union { unsigned u; float f; } v; v.u = ((unsigned)h) << 16;
    return v.f;
}

// ---------------------------------------------------------------------------
// Graph structure (compile-time), matching Python enumeration order.
// ---------------------------------------------------------------------------
struct AdjT {
    int src[120];
    int dst[120];
    int cnt[36];
    int idx[36][4];    // incoming edges per node
    int ostart[36];    // outgoing edge run start
    int ocnt[36];      // outgoing edge run length
};

constexpr AdjT build_adj() {
    AdjT a{};
    const int ddx[4] = {-1, 0, 0, 1};
    const int ddy[4] = {0, -1, 1, 0};
    int ne = 0;
    for (int i = 0; i < 6; i++)
        for (int j = 0; j < 6; j++)
            for (int d = 0; d < 4; d++) {
                int x = i + ddx[d], y = j + ddy[d];
                if (x >= 0 && x < 6 && y >= 0 && y < 6) {
                    a.src[ne] = j * 6 + i;
                    a.dst[ne] = y * 6 + x;
                    ne++;
                }
            }
    for (int n = 0; n < 36; n++) {
        a.cnt[n] = 0;
        for (int e = 0; e < 120; e++)
            if (a.dst[e] == n) a.idx[n][a.cnt[n]++] = e;
    }
    for (int n = 0; n < 36; n++) { a.ostart[n] = 0; a.ocnt[n] = 0; }
    for (int e = 0; e < 120; e++) {
        a.ocnt[a.src[e]]++;
        if (e == 0 || a.src[e] != a.src[e - 1]) a.ostart[a.src[e]] = e;
    }
    return a;
}

__device__ constexpr AdjT ADJC = build_adj();
__device__ constexpr int G16_START[17] =
    {0, 3, 6, 9, 12, 14, 16, 18, 20, 22, 24, 26, 28, 30, 32, 34, 36};

// ---------------------------------------------------------------------------
// K0: weight prep — B-fragments (bf16) for conv2/conv3/conv4 MFMA.
// ---------------------------------------------------------------------------
__global__ __launch_bounds__(256) void k_prep(const float* __restrict__ w2,
                                              const float* __restrict__ w3,
                                              const float* __restrict__ w4,
                                              unsigned short* __restrict__ wp2,
                                              unsigned short* __restrict__ wp3,
                                              unsigned short* __restrict__ wp4) {
    int e = blockIdx.x * 256 + threadIdx.x;
    if (e < 25600) {
        int j = e & 7, lane = (e >> 3) & 63, ct = (e >> 9) & 1, t = e >> 10;
        int co = ct * 16 + (lane & 15), ci = (lane >> 4) * 8 + j;
        wp2[e] = f2bf(w2[co * 800 + ci * 25 + t]);
    } else if (e < 76800) {
        int e3 = e - 25600;
        int j = e3 & 7, lane = (e3 >> 3) & 63, nt = (e3 >> 9) & 3, t = e3 >> 11;
        int co = nt * 16 + (lane & 15), ci = (lane >> 4) * 8 + j;
        wp3[e3] = f2bf(w3[(co * 32 + ci) * 25 + t]);
    } else {
        int e4 = e - 76800;
        int j = e4 & 7, lane = (e4 >> 3) & 63, nt = (e4 >> 9) & 3;
        int ks = (e4 >> 11) & 1, t = e4 >> 12;
        int co = nt * 16 + (lane & 15), ci = ks * 32 + (lane >> 4) * 8 + j;
        wp4[e4] = f2bf(w4[(co * 64 + ci) * 25 + t]);
    }
}

// ---------------------------------------------------------------------------
// K0b: weight prep for heads MFMA (verified R4).
// ---------------------------------------------------------------------------
__global__ __launch_bounds__(256) void k_prep2(const float* __restrict__ cnw1,
                                               const float* __restrict__ epw1,
                                               const float* __restrict__ cnw2,
                                               const float* __restrict__ epw2,
                                               unsigned short* __restrict__ wph1,
                                               unsigned short* __restrict__ wpcn2,
                                               unsigned short* __restrict__ wpep2) {
    int e = blockIdx.x * 256 + threadIdx.x;
    if (e < 131072) {
        int j = e & 7, lane = (e >> 3) & 63, nt = (e >> 9) & 31, kt = e >> 14;
        int c = nt * 16 + (lane & 15);
        int k = kt * 32 + ((lane >> 4) << 3) + j;
        float v = (c < 256) ? cnw1[c * 256 + k] : epw1[(c - 256) * 256 + k];
        wph1[e] = f2bf(v);
    } else if (e < 163840) {
        int e2 = e - 131072;
        int j = e2 & 7, lane = (e2 >> 3) & 63, nt = (e2 >> 9) & 7, kt = e2 >> 12;
        int c = nt * 16 + (lane & 15);
        int k = kt * 32 + ((lane >> 4) << 3) + j;
        wpcn2[e2] = f2bf(c < 120 ? cnw2[c * 256 + k] : 0.f);
    } else {
        int e3 = e - 163840;
        int j = e3 & 7, lane = (e3 >> 3) & 63, idx = e3 >> 9;
        int kt = idx / 3, nt = idx - kt * 3;
        int c = nt * 16 + (lane & 15);
        int k = kt * 32 + ((lane >> 4) << 3) + j;
        wpep2[e3] = f2bf(c < 36 ? epw2[c * 256 + k] : 0.f);
    }
}

// ---------------------------------------------------------------------------
// K12: FUSED conv1 + conv2 + maxpool2.
// Block = half image (grid B*2), 128 threads (2 waves).
//  Phase A (conv1, VALU): stage 20 image rows (2.5 KB) -> 112 threads compute
//    the block's 448 conv1 positions x 32 ch (window in regs, weights via
//    wave-uniform s_loads) -> s_buf bf16 ch-last stride 40 (b128 LDS writes).
//    conv1 output NEVER touches global (R5's 59 us kernel + 103 MB+RFO gone).
//  Phase B (conv2, MFMA): identical to verified R5 tap-GEMM on s_buf;
//    stage/pool epilogue unioned onto s_buf; out = p2 ch-last bf16 [144][32].
// LDS 2880 + 35840 = 38.7 KB -> 4 blocks/CU.
// ---------------------------------------------------------------------------
__global__ __launch_bounds__(128) void k_conv12(const float* __restrict__ img,
                                                const float* __restrict__ w1,
                                                const float* __restrict__ b1,
                                                const unsigned short* __restrict__ wprep,
                                                const float* __restrict__ bias2,
                                                unsigned short* __restrict__ out) {
    __shared__ float s_img[20 * 36];            // 20 rows x 32 cols, stride 36
    __shared__ unsigned short s_buf[448 * 40];  // conv1 out [448][40]; later stage [288][40]
    const int blk = blockIdx.x;
    const int b = blk >> 1, half = blk & 1;
    const int tid = threadIdx.x;
    const int lane = tid & 63, wave = tid >> 6;
    const int m = lane & 15, quad = lane >> 4;

    // stage image rows half*12 .. half*12+19 (640 floats = 160 float4)
    {
        const float4* g4 = (const float4*)(img + (size_t)b * 1024 + half * 12 * 32);
        for (int v = tid; v < 160; v += 128) {
            float4 t = g4[v];
            *(float4*)(s_img + (v >> 3) * 36 + (v & 7) * 4) = t;
        }
    }

    // conv2 B-frag prefetch (global, no LDS dependency)
    const short8* wp = (const short8*)wprep;
    short8 bw0 = wp[lane];
    short8 bw1 = wp[64 + lane];

    __syncthreads();

    // ---- phase A: conv1 ----
    if (tid < 112) {
        const int y = tid / 7;
        const int xg = (tid - y * 7) * 4;
        float win[5][8];
#pragma unroll
        for (int r = 0; r < 5; r++) {
            float4 v0 = *(const float4*)(s_img + (y + r) * 36 + xg);
            float4 v1 = *(const float4*)(s_img + (y + r) * 36 + xg + 4);
            win[r][0] = v0.x; win[r][1] = v0.y; win[r][2] = v0.z; win[r][3] = v0.w;
            win[r][4] = v1.x; win[r][5] = v1.y; win[r][6] = v1.z; win[r][7] = v1.w;
        }
        unsigned res[4][16];  // [pos in group][co pair] packed bf16x2
#pragma unroll 4
        for (int cp = 0; cp < 16; cp++) {
            float bb0 = b1[2 * cp], bb1 = b1[2 * cp + 1];
            float a0[4], a1[4];
#pragma unroll
            for (int p = 0; p < 4; p++) { a0[p] = bb0; a1[p] = bb1; }
            const float* w0 = w1 + 2 * cp * 25;
            const float* wB = w0 + 25;
#pragma unroll
            for (int ky = 0; ky < 5; ky++)
#pragma unroll
                for (int kx = 0; kx < 5; kx++) {
                    float wv0 = w0[ky * 5 + kx], wv1 = wB[ky * 5 + kx];
#pragma unroll
                    for (int p = 0; p < 4; p++) {
                        float iv = win[ky][kx + p];
                        a0[p] += iv * wv0;
                        a1[p] += iv * wv1;
                    }
                }
#pragma unroll
            for (int p = 0; p < 4; p++)
                res[p][cp] = (unsigned)f2bf(a0[p]) | ((unsigned)f2bf(a1[p]) << 16);
        }
#pragma unroll
        for (int i = 0; i < 4; i++) {
            int p = y * 28 + xg + i;
            unsigned* dst = (unsigned*)(s_buf + p * 40);
#pragma unroll
            for (int j = 0; j < 4; j++)
                ((uint4*)dst)[j] = make_uint4(res[i][4 * j], res[i][4 * j + 1],
                                              res[i][4 * j + 2], res[i][4 * j + 3]);
        }
    }
    __syncthreads();

    // ---- phase B: conv2 tap-GEMM (verified R5 structure) ----
    int a_idx[9];
#pragma unroll
    for (int mt = 0; mt < 9; mt++) {
        int p = wave * 144 + mt * 16 + m;
        int yl = p / 24;
        int x = p - yl * 24;
        a_idx[mt] = (yl * 28 + x) * 40 + quad * 8;
    }

    float4v acc[9][2];
#pragma unroll
    for (int mt = 0; mt < 9; mt++) {
        acc[mt][0] = (float4v){0.f, 0.f, 0.f, 0.f};
        acc[mt][1] = (float4v){0.f, 0.f, 0.f, 0.f};
    }

    for (int t = 0; t < 25; t++) {
        short8 nb0, nb1;
        if (t < 24) {
            nb0 = wp[(t + 1) * 128 + lane];
            nb1 = wp[(t + 1) * 128 + 64 + lane];
        }
        const int ky = t / 5, kx = t - ky * 5;
        const int toff = (ky * 28 + kx) * 40;
#pragma unroll
        for (int mt = 0; mt < 9; mt++) {
            short8 av = *(const short8*)(s_buf + a_idx[mt] + toff);
            acc[mt][0] = __builtin_amdgcn_mfma_f32_16x16x32_bf16(av, bw0, acc[mt][0], 0, 0, 0);
            acc[mt][1] = __builtin_amdgcn_mfma_f32_16x16x32_bf16(av, bw1, acc[mt][1], 0, 0, 0);
        }
        if (t < 24) { bw0 = nb0; bw1 = nb1; }
    }

    __syncthreads();  // all A-reads done before stage overwrites s_buf

    const int n = lane & 15;
#pragma unroll
    for (int mt = 0; mt < 9; mt++) {
        int pbase = wave * 144 + mt * 16 + quad * 4;
#pragma unroll
        for (int r = 0; r < 4; r++) {
            s_buf[(pbase + r) * 40 + n] = f2bf(acc[mt][0][r]);
            s_buf[(pbase + r) * 40 + 16 + n] = f2bf(acc[mt][1][r]);
        }
    }
    __syncthreads();

    unsigned short* op = out + (size_t)b * 4608;
    for (int i = tid; i < 2304; i += 128) {
        int co = i & 31;
        int pos = i >> 5;
        int prl = pos / 12;
        int px = pos - prl * 12;
        int base = ((prl * 2) * 24 + px * 2) * 40 + co;
        float v0 = bf2f(s_buf[base]);
        float v1 = bf2f(s_buf[base + 40]);
        float v2 = bf2f(s_buf[base + 24 * 40]);
        float v3 = bf2f(s_buf[base + 25 * 40]);
        float mx = fmaxf(fmaxf(v0, v1), fmaxf(v2, v3));
        op[((half * 6 + prl) * 12 + px) * 32 + co] = f2bf(mx + bias2[co]);
    }
}

// ---------------------------------------------------------------------------
// K34: fused conv3 + conv4 + pool + flatten via MFMA tap-GEMM (verified R3-R5).
// ---------------------------------------------------------------------------
__global__ __launch_bounds__(64) void k_conv34(const unsigned short* __restrict__ p2,
                                               const unsigned short* __restrict__ wp3,
                                               const float* __restrict__ b3,
                                               const unsigned short* __restrict__ wp4,
                                               const float* __restrict__ b4,
                                               unsigned short* __restrict__ emb) {
    __shared__ unsigned short s_buf34[9216];  // s_in [0,4608) | s_c3 [4608,9216)
    unsigned short* s_in = s_buf34;
    unsigned short* s_c3 = s_buf34 + 4608;    // [64][72] padded
    float* s_c4 = (float*)s_buf34;            // [16][64] — reuses s_in region
    const int b = blockIdx.x, tid = threadIdx.x;
    const int m = tid & 15, q = tid >> 4;

    {
        const short8* g8 = (const short8*)(p2 + (size_t)b * 4608);
        short8* s8 = (short8*)s_in;
        for (int i = tid; i < 576; i += 64) s8[i] = g8[i];
    }

    int a_base[4];
#pragma unroll
    for (int mt = 0; mt < 4; mt++) {
        int p = mt * 16 + m;
        int y = p >> 3, x = p & 7;
        a_base[mt] = (y * 12 + x) * 32 + q * 8;
    }

    float4v acc3[4][4];
#pragma unroll
    for (int mt = 0; mt < 4; mt++)
#pragma unroll
        for (int nt = 0; nt < 4; nt++) acc3[mt][nt] = (float4v){0.f, 0.f, 0.f, 0.f};

    const short8* wp = (const short8*)wp3;
    short8 bw[4];
#pragma unroll
    for (int nt = 0; nt < 4; nt++) bw[nt] = wp[nt * 64 + tid];

    __syncthreads();

    for (int t = 0; t < 25; t++) {
        short8 nb[4];
        if (t < 24) {
#pragma unroll
            for (int nt = 0; nt < 4; nt++) nb[nt] = wp[((t + 1) * 4 + nt) * 64 + tid];
        }
        const int ky = t / 5, kx = t - ky * 5;
        const int toff = (ky * 12 + kx) * 32;
#pragma unroll
        for (int mt = 0; mt < 4; mt++) {
            short8 av = *(const short8*)(s_in + a_base[mt] + toff);
#pragma unroll
            for (int nt = 0; nt < 4; nt++)
                acc3[mt][nt] = __builtin_amdgcn_mfma_f32_16x16x32_bf16(av, bw[nt], acc3[mt][nt], 0, 0, 0);
        }
        if (t < 24) {
#pragma unroll
            for (int nt = 0; nt < 4; nt++) bw[nt] = nb[nt];
        }
    }

    {
        float bb[4];
#pragma unroll
        for (int nt = 0; nt < 4; nt++) bb[nt] = b3[nt * 16 + m];
#pragma unroll
        for (int mt = 0; mt < 4; mt++)
#pragma unroll
            for (int nt = 0; nt < 4; nt++)
#pragma unroll
                for (int r = 0; r < 4; r++)
                    s_c3[(mt * 16 + q * 4 + r) * 72 + nt * 16 + m] =
                        f2bf(acc3[mt][nt][r] + bb[nt]);
    }
    __syncthreads();

    const int a4_base = ((m >> 2) * 8 + (m & 3)) * 72 + q * 8;
    float4v acc4[4];
#pragma unroll
    for (int nt = 0; nt < 4; nt++) acc4[nt] = (float4v){0.f, 0.f, 0.f, 0.f};

    const short8* wq = (const short8*)wp4;
    short8 cw[8];
#pragma unroll
    for (int i = 0; i < 8; i++) cw[i] = wq[i * 64 + tid];

    for (int t = 0; t < 25; t++) {
        short8 nb[8];
        if (t < 24) {
#pragma unroll
            for (int i = 0; i < 8; i++) nb[i] = wq[((t + 1) * 8 + i) * 64 + tid];
        }
        const int ky = t / 5, kx = t - ky * 5;
        const int toff = (ky * 8 + kx) * 72;
#pragma unroll
        for (int ks = 0; ks < 2; ks++) {
            short8 av = *(const short8*)(s_c3 + a4_base + toff + ks * 32);
#pragma unroll
            for (int nt = 0; nt < 4; nt++)
                acc4[nt] = __builtin_amdgcn_mfma_f32_16x16x32_bf16(av, cw[ks * 4 + nt], acc4[nt], 0, 0, 0);
        }
        if (t < 24) {
#pragma unroll
            for (int i = 0; i < 8; i++) cw[i] = nb[i];
        }
    }

    __syncthreads();

#pragma unroll
    for (int nt = 0; nt < 4; nt++)
#pragma unroll
        for (int r = 0; r < 4; r++)
            s_c4[(q * 4 + r) * 64 + nt * 16 + m] = acc4[nt][r];
    __syncthreads();

    {
        float bb = b4[tid];
        ushort4v res;
#pragma unroll
        for (int pp = 0; pp < 4; pp++) {
            int y0 = (pp >> 1) * 2, x0 = (pp & 1) * 2;
            float v0 = s_c4[(y0 * 4 + x0) * 64 + tid];
            float v1 = s_c4[(y0 * 4 + x0 + 1) * 64 + tid];
            float v2 = s_c4[((y0 + 1) * 4 + x0) * 64 + tid];
            float v3 = s_c4[((y0 + 1) * 4 + x0 + 1) * 64 + tid];
            res[pp] = f2bf(fmaxf(fmaxf(v0, v1), fmaxf(v2, v3)) + bb);
        }
        *(ushort4v*)(emb + (size_t)b * 256 + tid * 4) = res;
    }
}

// ---------------------------------------------------------------------------
// K5: fused heads (MFMA) + DAMP recurrence (verified R4/R5).
// ---------------------------------------------------------------------------
__global__ __launch_bounds__(256) void k_heads(
    const unsigned short* __restrict__ emb,
    const unsigned short* __restrict__ wph1,
    const float* __restrict__ cn_b1, const float* __restrict__ ep_b1,
    const unsigned short* __restrict__ wpcn2, const float* __restrict__ cn_b2,
    const unsigned short* __restrict__ wpep2, const float* __restrict__ ep_b2,
    float* __restrict__ out) {
    __shared__ unsigned short s_hid[16 * 520];
    __shared__ float s_conn[120 * 17];
    __shared__ float s_rec0[120 * 17];
    __shared__ float s_rec1[120 * 17];
    __shared__ float s_ep[36 * 17];
    const int tid = threadIdx.x;
    const int lane = tid & 63, wave = tid >> 6;
    const int m = lane & 15, q = lane >> 4;
    const int b0 = blockIdx.x * 16;

    float4v acc[8];
#pragma unroll
    for (int i = 0; i < 8; i++) acc[i] = (float4v){0.f, 0.f, 0.f, 0.f};
    const short8* wp1 = (const short8*)wph1;
    for (int kt = 0; kt < 8; kt++) {
        short8 av = *(const short8*)(emb + (size_t)(b0 + m) * 256 + kt * 32 + q * 8);
#pragma unroll
        for (int ntl = 0; ntl < 8; ntl++) {
            int nt = wave * 8 + ntl;
            short8 bv = wp1[(kt * 32 + nt) * 64 + lane];
            acc[ntl] = __builtin_amdgcn_mfma_f32_16x16x32_bf16(av, bv, acc[ntl], 0, 0, 0);
        }
    }
#pragma unroll
    for (int ntl = 0; ntl < 8; ntl++) {
        int c = (wave * 8 + ntl) * 16 + m;
        float bb = (c < 256) ? cn_b1[c] : ep_b1[c - 256];
#pragma unroll
        for (int r = 0; r < 4; r++)
            s_hid[(q * 4 + r) * 520 + c] = f2bf(fmaxf(acc[ntl][r] + bb, 0.f));
    }
    __syncthreads();

    for (int job = wave; job < 11; job += 4) {
        const bool isconn = job < 8;
        const int koff = isconn ? 0 : 256;
        float4v a2 = (float4v){0.f, 0.f, 0.f, 0.f};
        for (int kt = 0; kt < 8; kt++) {
            short8 av = *(const short8*)(s_hid + m * 520 + koff + kt * 32 + q * 8);
            short8 bv = isconn
                ? ((const short8*)wpcn2)[(kt * 8 + job) * 64 + lane]
                : ((const short8*)wpep2)[(kt * 3 + (job - 8)) * 64 + lane];
            a2 = __builtin_amdgcn_mfma_f32_16x16x32_bf16(av, bv, a2, 0, 0, 0);
        }
        int c = (isconn ? job : (job - 8)) * 16 + m;
        float bb = isconn ? (c < 120 ? cn_b2[c] : 0.f) : (c < 36 ? ep_b2[c] : 0.f);
#pragma unroll
        for (int r = 0; r < 4; r++) {
            float v = 1.f / (1.f + __expf(-(a2[r] + bb)));
            int row = q * 4 + r;
            if (isconn) {
                if (c < 120) { s_conn[c * 17 + row] = v; s_rec0[c * 17 + row] = v; }
            } else {
                if (c < 36) s_ep[c * 17 + row] = v;
            }
        }
    }
    __syncthreads();

    const int row = tid >> 4, g = tid & 15;
    const int ns = G16_START[g];
    const int nodecnt = G16_START[g + 1] - ns;
    int ie[3][4], icnt[3], os[3], oc[3];
    float cr[3][4];
#pragma unroll
    for (int s = 0; s < 3; s++) {
        if (s < nodecnt) {
            int n = ns + s;
            icnt[s] = ADJC.cnt[n];
#pragma unroll
            for (int qx = 0; qx < 4; qx++) ie[s][qx] = ADJC.idx[n][qx];
            os[s] = ADJC.ostart[n];
            oc[s] = ADJC.ocnt[n];
#pragma unroll
            for (int oe = 0; oe < 4; oe++)
                cr[s][oe] = (oe < oc[s]) ? s_conn[(os[s] + oe) * 17 + row] : 0.f;
        } else {
            icnt[s] = 0; oc[s] = 0; os[s] = 0;
#pragma unroll
            for (int qx = 0; qx < 4; qx++) ie[s][qx] = 0;
#pragma unroll
            for (int oe = 0; oe < 4; oe++) cr[s][oe] = 0.f;
        }
    }
    float old0 = (g == 0) ? s_conn[0 * 17 + row] : 0.f;

    for (int it = 0; it < 36; it++) {
        const float* cur = (it & 1) ? s_rec1 : s_rec0;
        float* nxt = (it & 1) ? s_rec0 : s_rec1;
#pragma unroll
        for (int s = 0; s < 3; s++) {
            float sum = 0.f;
#pragma unroll
            for (int qx = 0; qx < 4; qx++)
                sum += (qx < icnt[s]) ? cur[ie[s][qx] * 17 + row] : 0.f;
            sum = fminf(sum, 1.f);
#pragma unroll
            for (int oe = 0; oe < 4; oe++) {
                if (oe < oc[s]) {
                    int e = os[s] + oe;
                    float nv = sum * cr[s][oe];
                    nxt[e * 17 + row] = nv;
                    if (g == 0 && s == 0 && oe == 0)
                        old0 = fminf(old0 + nv, 1.f);
                }
            }
        }
        __syncthreads();
    }

    if (g == 0)
        out[b0 + row] = old0 * s_ep[0 * 17 + row] * s_ep[6 * 17 + row];
}

// ---------------------------------------------------------------------------
extern "C" void kernel_launch(void* const* d_in, const int* in_sizes, int n_in,
                              void* d_out, int out_size, void* d_ws, size_t ws_size,
                              hipStream_t stream) {
    const float* image = (const float*)d_in[0];
    const float* c1w = (const float*)d_in[1];
    const float* c1b = (const float*)d_in[2];
    const float* c2w = (const float*)d_in[3];
    const float* c2b = (const float*)d_in[4];
    const float* c3w = (const float*)d_in[5];
    const float* c3b = (const float*)d_in[6];
    const float* c4w = (const float*)d_in[7];
    const float* c4b = (const float*)d_in[8];
    const float* epw1 = (const float*)d_in[9];
    const float* epb1 = (const float*)d_in[10];
    const float* epw2 = (const float*)d_in[11];
    const float* epb2 = (const float*)d_in[12];
    const float* cnw1 = (const float*)d_in[13];
    const float* cnb1 = (const float*)d_in[14];
    const float* cnw2 = (const float*)d_in[15];
    const float* cnb2 = (const float*)d_in[16];

    const int B = in_sizes[0] / (32 * 32);  // 1024

    unsigned short* ws = (unsigned short*)d_ws;
    unsigned short* p2 = ws;                              // B*4608 bf16
    unsigned short* embo = p2 + (size_t)B * 4608;         // B*256 bf16
    unsigned short* wp2 = embo + (size_t)B * 256;         // 25600
    unsigned short* wp3 = wp2 + 25600;                    // 51200
    unsigned short* wp4 = wp3 + 51200;                    // 102400
    unsigned short* wph1 = wp4 + 102400;                  // 131072
    unsigned short* wpcn2 = wph1 + 131072;                // 32768
    unsigned short* wpep2 = wpcn2 + 32768;                // 12288

    k_prep<<<700, 256, 0, stream>>>(c2w, c3w, c4w, wp2, wp3, wp4);
    k_prep2<<<688, 256, 0, stream>>>(cnw1, epw1, cnw2, epw2, wph1, wpcn2, wpep2);
    k_conv12<<<B * 2, 128, 0, stream>>>(image, c1w, c1b, wp2, c2b, p2);
    k_conv34<<<B, 64, 0, stream>>>(p2, wp3, c3b, wp4, c4b, embo);
    k_heads<<<B / 16, 256, 0, stream>>>(embo, wph1, cnb1, epb1,
                                        wpcn2, cnb2, wpep2, epb2, (float*)d_out);
}